// Round 3
// baseline (113.318 us; speedup 1.0000x reference)
//
#include <hip/hip_runtime.h>
#include <math.h>

// Problem constants (from reference setup_inputs)
constexpr int N_ = 16;
constexpr int K_ = 32768;
constexpr int C_ = 16;
constexpr int M_ = 128;

constexpr int KC = 512;              // k's staged per pass
constexpr int CPB = 2;               // chunks (passes) per block
constexpr int CPW = K_ / (KC * CPB); // 32 blocks per n -> 512 blocks, 2/CU
constexpr int WAVES = 8;             // waves per block (512 threads)

// ws poison: harness re-poisons d_ws to 0xAA before every launch. cnt
// counters start at (int)0xAAAAAAAA (accept 0 base as fallback). rowwin
// slots are written unconditionally by every block before its release, so
// poison is never read there.
#define POISON_U 0xAAAAAAAAu

// Agent-scope accessors: coherence-point loads/stores, NO cache-wide wb/inv
// (R3 lesson: all-thread __threadfence() cost 3x).
__device__ __forceinline__ unsigned long long load_agent_u64(
    const unsigned long long* p) {
  return __hip_atomic_load(p, __ATOMIC_RELAXED, __HIP_MEMORY_SCOPE_AGENT);
}
__device__ __forceinline__ void store_agent_u64(unsigned long long* p,
                                                unsigned long long v) {
  __hip_atomic_store(p, v, __ATOMIC_RELAXED, __HIP_MEMORY_SCOPE_AGENT);
}
__device__ __forceinline__ void store_agent_f32(float* p, float v) {
  __hip_atomic_store(p, v, __ATOMIC_RELAXED, __HIP_MEMORY_SCOPE_AGENT);
}
__device__ __forceinline__ float load_agent_f32(const float* p) {
  return __hip_atomic_load(p, __ATOMIC_RELAXED, __HIP_MEMORY_SCOPE_AGENT);
}

// R16 (kept): single-instruction float min/max (bypass IEEE canonicalization
// hipcc inserts around fminf/fmaxf). Bit-exact for finite inputs.
__device__ __forceinline__ float vminf_(float a, float b) {
  float r;
  asm("v_min_f32 %0, %1, %2" : "=v"(r) : "v"(a), "v"(b));
  return r;
}
__device__ __forceinline__ float vmaxf_(float a, float b) {
  float r;
  asm("v_max_f32 %0, %1, %2" : "=v"(r) : "v"(a), "v"(b));
  return r;
}
__device__ __forceinline__ float vmax0_(float a) {  // max(a, 0.0f)
  float r;
  asm("v_max_f32 %0, 0, %1" : "=v"(r) : "v"(a));
  return r;
}
// key = (iou_bits & 0xFFFFFE00) | (idx6 & 0x1FF) in ONE v_bfi_b32.
__device__ __forceinline__ int vbfi_key_(unsigned mask, unsigned iou_bits,
                                         unsigned idx6) {
  int r;
  asm("v_bfi_b32 %0, %1, %2, %3" : "=v"(r) : "v"(mask), "v"(iou_bits),
      "v"(idx6));
  return r;
}

// ---------------------------------------------------------------------------
// R17 = R16 (proven: LDS staging, hoisted a1, 4 rows/lane ILP, asm
// min/max/bfi, packed-int-key argmax, CPB=2 in-register chunk merge,
// relaxed-store publish, absmax 0.0) with the pass schedule de-serialized:
//   * lds4/ldsa1 double-buffered [CPB][KC]: pass-1 staging writes need NO
//     preceding barrier (pass-0 readers are on buffer 0).
//   * BOTH passes' pred_boxes loads issued at kernel entry — their HBM
//     latencies overlap; pass-1 data waits in VGPRs until after pass-0
//     compute (empty-asm pin forces early materialization).
//   * main-loop barriers: 4 -> 3.
// Numerics byte-identical to R16 (same ops, same order, same key encoding).
// Target: the ~38% VALU-idle (stage->bar->compute serialization).
// ---------------------------------------------------------------------------
__global__ __launch_bounds__(512, 4) void fused_loss_kernel(
    const float* __restrict__ pred_boxes,
    const float* __restrict__ pred_cls,
    const float* __restrict__ target,
    unsigned long long* __restrict__ rowwin,  // [N_][CPW][M_]
    float* __restrict__ ws2,                  // [N_][8]
    int* __restrict__ cnt,                    // [N_+1]
    float* __restrict__ out) {
  __shared__ float4 lds4[CPB][KC];
  __shared__ float ldsa1[CPB][KC];
  __shared__ int key_s[WAVES][CPB][M_];
  __shared__ float red[WAVES][7];
  __shared__ int s_flag;

  const int bx = blockIdx.x;  // 0..CPW-1
  const int n = blockIdx.y;
  const int tid = threadIdx.x;

  const int wv = tid >> 6;          // wave id 0..7
  const int lane = tid & 63;
  const int rb = lane & 31;         // row base: rows rb + 32*j
  const int half = (lane >> 5) & 1; // k-half within the wave's slice pair
  const int ks = (wv * 2 + half) * 32;       // this lane's 32-k slice
  const int hbase = ((1 - half) << 5) | 31;  // idx6 = hbase - kl (bits 0-5)

  // ---- issue BOTH passes' staging loads up-front (latencies overlap) ----
  const float* p0 =
      pred_boxes + ((size_t)(n * K_ + bx * (CPB * KC) + tid)) * 5;
  const float x0 = p0[0], y0 = p0[1], w0 = p0[2], h0 = p0[3];
  const float* p1 = p0 + (size_t)KC * 5;
  float x1 = p1[0], y1 = p1[1], w1 = p1[2], h1 = p1[3];

  // per-lane target values for 4 rows (tboxes = target[...,1:])
  float tx1[4], ty1[4], tx2[4], ty2[4], a2[4];
#pragma unroll
  for (int j = 0; j < 4; ++j) {
    const float* tg = target + ((size_t)(n * M_ + rb + 32 * j)) * 5;
    tx1[j] = tg[1];
    ty1[j] = tg[2];
    tx2[j] = tg[3] + 1.0f;
    ty2[j] = tg[4] + 1.0f;
    a2[j] = (tg[3] - tg[1] + 1.0f) * (tg[4] - tg[2] + 1.0f) + 1e-16f;
  }

  // ---- stage pass 0 (ref-exact derived values) ----
  {
    const float px2 = w0 + x0;  // ref: pb[...,2] + pb[...,0]
    const float py2 = h0 + y0;
    lds4[0][tid] = make_float4(x0, y0, px2 + 1.0f, py2 + 1.0f);
    // ref-exact: a1 = (p_x2 - p_x1 + 1) * (p_y2 - p_y1 + 1)
    ldsa1[0][tid] = (px2 - x0 + 1.0f) * (py2 - y0 + 1.0f);
  }
  // pin pass-1 regs: forces the loads to complete here (concurrent with
  // pass-0's) instead of being sunk below the barrier.
  asm volatile("" : "+v"(x1), "+v"(y1), "+v"(w1), "+v"(h1));
  __syncthreads();  // buf0 ready

  const unsigned keymask = 0xFFFFFE00u;  // hoisted into a VGPR once

#define COMPUTE_PASS(B, BEST)                                              \
  _Pragma("unroll 8") for (int kl = 0; kl < 32; ++kl) {                    \
    const float4 v = lds4[B][ks + kl];                                     \
    const float a1 = ldsa1[B][ks + kl];                                    \
    const unsigned idx6 = (unsigned)(hbase - kl);                          \
    _Pragma("unroll") for (int j = 0; j < 4; ++j) {                        \
      float ww = vminf_(v.z, tx2[j]) - vmaxf_(v.x, tx1[j]);                \
      float hh = vminf_(v.w, ty2[j]) - vmaxf_(v.y, ty1[j]);                \
      ww = vmax0_(ww);                                                     \
      hh = vmax0_(hh);                                                     \
      const float inter = ww * hh;                                         \
      const float iou =                                                    \
          inter * __builtin_amdgcn_rcpf((a1 + a2[j]) - inter);             \
      const int key = vbfi_key_(keymask, __float_as_uint(iou), idx6);      \
      BEST[j] = BEST[j] > key ? BEST[j] : key;                             \
    }                                                                      \
  }

#define MERGE_PUBLISH(B, BEST)                                             \
  _Pragma("unroll") for (int j = 0; j < 4; ++j) {                          \
    const int other = __shfl_xor(BEST[j], 32, 64);                         \
    BEST[j] = BEST[j] > other ? BEST[j] : other;                           \
  }                                                                        \
  if (lane < 32) {                                                         \
    const unsigned wvf = (unsigned)(7 - wv) << 6;                          \
    _Pragma("unroll") for (int j = 0; j < 4; ++j) {                        \
      const unsigned u = (unsigned)BEST[j];                                \
      key_s[wv][B][rb + 32 * j] =                                          \
          (int)((u & 0xFFFFFE00u) | wvf | (u & 63u));                      \
    }                                                                      \
  }

  // ---- pass 0 compute + publish ----
  {
    int best0[4];
#pragma unroll
    for (int j = 0; j < 4; ++j) best0[j] = (int)0x80000000;
    COMPUTE_PASS(0, best0)
    MERGE_PUBLISH(0, best0)
  }

  // ---- stage pass 1 from regs (distinct buffer: NO barrier needed) ----
  {
    const float px2 = w1 + x1;
    const float py2 = h1 + y1;
    lds4[1][tid] = make_float4(x1, y1, px2 + 1.0f, py2 + 1.0f);
    ldsa1[1][tid] = (px2 - x1 + 1.0f) * (py2 - y1 + 1.0f);
  }
  __syncthreads();  // buf1 ready AND key_s[*][0] visible

  // ---- pass 1 compute + publish ----
  {
    int best1[4];
#pragma unroll
    for (int j = 0; j < 4; ++j) best1[j] = (int)0x80000000;
    COMPUTE_PASS(1, best1)
    MERGE_PUBLISH(1, best1)
  }
  __syncthreads();  // key_s[*][1] visible

  // 8-way wave merge per chunk (pure v_max_i32), exact u64 cross-chunk merge
  // in-register, then ONE relaxed agent store per row per block (no RMW).
  if (tid < M_) {
    unsigned long long bestu = ~0ull;
#pragma unroll
    for (int cc = 0; cc < CPB; ++cc) {
      int mg = key_s[0][cc][tid];
#pragma unroll
      for (int w2 = 1; w2 < WAVES; ++w2) {
        const int v = key_s[w2][cc][tid];
        mg = mg > v ? mg : v;
      }
      const unsigned e = (unsigned)mg & 511u;
      const int gk = (bx * CPB + cc) * KC + (511 - (int)e);  // winner's k
      const unsigned tr = (unsigned)mg & 0xFFFFFE00u;        // trunc iou bits
      const unsigned ord = tr ^ (unsigned)(((int)tr >> 31) | 0x80000000);
      const unsigned long long u =
          ((unsigned long long)(~ord) << 32) | (unsigned)gk;
      bestu = u < bestu ? u : bestu;  // ties -> smaller global k (cc=0 first)
    }
    store_agent_u64(&rowwin[((size_t)n * CPW + bx) * M_ + tid], bestu);
  }

  // Release: barrier drains each wave's vmcnt(0); then one relaxed signal.
  __syncthreads();
  if (tid == 0) {
    const unsigned old = (unsigned)atomicAdd(&cnt[n], 1);
    s_flag = (old == POISON_U + (CPW - 1)) || (old == CPW - 1);
  }
  __syncthreads();
  if (!s_flag) return;

  // ================= Phase 2: last block for this n =================
  {
    const int m = tid & (M_ - 1);
    float acc[7] = {0, 0, 0, 0, 0, 0, 0};
    if (tid < M_) {
      // merge the CPW slot keys (min == global first-max argmax)
      unsigned long long bestk = ~0ull;
#pragma unroll
      for (int g = 0; g < CPW; ++g) {
        const unsigned long long pk =
            load_agent_u64(&rowwin[((size_t)n * CPW + g) * M_ + m]);
        bestk = pk < bestk ? pk : bestk;
      }
      const int bidx0 = (int)(unsigned)bestk;  // low 32 bits = winning k

      const float* tg2 = target + ((size_t)(n * M_ + m)) * 5;
      const float t0 = tg2[0], t1 = tg2[1], t2 = tg2[2], t3 = tg2[3],
                  t4 = tg2[4];
      const float sum5 = t0 + t1 + t2 + t3 + t4;
      const float mk = (sum5 != 0.0f) ? 1.0f : 0.0f;
      const int bidx = (sum5 != 0.0f) ? bidx0 : 0;

      const float* pb = pred_boxes + ((size_t)(n * K_ + bidx)) * 5;
      const float b0 = pb[0], b1 = pb[1], bw = pb[2], bh = pb[3];

      // cross-entropy via log-softmax over C=16
      const float4* pc =
          (const float4*)(pred_cls + ((size_t)(n * K_ + bidx)) * C_);
      float vals[C_];
#pragma unroll
      for (int q = 0; q < 4; ++q) {
        const float4 vv = pc[q];
        vals[q * 4 + 0] = vv.x;
        vals[q * 4 + 1] = vv.y;
        vals[q * 4 + 2] = vv.z;
        vals[q * 4 + 3] = vv.w;
      }
      int tcls = (int)t0;
      tcls = tcls < 0 ? 0 : (tcls >= C_ ? C_ - 1 : tcls);
      float mx = -INFINITY;
#pragma unroll
      for (int q = 0; q < C_; ++q) mx = fmaxf(mx, vals[q]);
      float se = 0.0f;
#pragma unroll
      for (int q = 0; q < C_; ++q) se += expf(vals[q] - mx);
      const float ce2 = logf(se) + mx - vals[tcls];

      const float dx = b0 - t1;
      const float dy = b1 - t2;
      const float dw = bw - (t3 - t1);
      const float dh = bh - (t4 - t2);

      // conf: conf_idx==0 => sigmoid(pred_boxes[n,0,4]) for every m
      const float pcf = pred_boxes[(size_t)n * K_ * 5 + 4];
      const float bc = 1.0f / (1.0f + expf(-pcf));
      const float bce = (bc > 0.5f) ? -logf(bc) : -logf(1.0f - bc);

      acc[0] = mk;
      acc[1] = mk * ce2;
      acc[2] = mk * dx * dx;
      acc[3] = mk * dy * dy;
      acc[4] = mk * dw * dw;
      acc[5] = mk * dh * dh;
      acc[6] = mk * bce;
    }

    // block reduce: 8 waves shuffle-reduce, LDS combine
#pragma unroll
    for (int i = 0; i < 7; ++i) {
      float v = acc[i];
      for (int off = 32; off > 0; off >>= 1) v += __shfl_down(v, off, 64);
      acc[i] = v;
    }
    const int lane2 = tid & 63;
    const int wid = tid >> 6;
    if (lane2 == 0) {
#pragma unroll
      for (int i = 0; i < 7; ++i) red[wid][i] = acc[i];
    }
    __syncthreads();

    if (tid == 0) {
      float sum7[7];
#pragma unroll
      for (int i = 0; i < 7; ++i) {
        float s = 0.0f;
#pragma unroll
        for (int w2 = 0; w2 < WAVES; ++w2) s += red[w2][i];
        sum7[i] = s;
      }
#pragma unroll
      for (int i = 0; i < 7; ++i) store_agent_f32(&ws2[n * 8 + i], sum7[i]);
    }
    __syncthreads();  // release: drains tid0's stores before the signal
    if (tid == 0) {
      const unsigned old2 = (unsigned)atomicAdd(&cnt[N_], 1);
      s_flag = (old2 == POISON_U + (N_ - 1)) || (old2 == N_ - 1);
    }
    __syncthreads();
  }

  // ================= Phase 3: global finalizer =================
  if (s_flag && tid == 0) {
    float s[7] = {0, 0, 0, 0, 0, 0, 0};
    for (int nn = 0; nn < N_; ++nn)
#pragma unroll
      for (int i = 0; i < 7; ++i) s[i] += load_agent_f32(&ws2[nn * 8 + i]);
    const float denom = s[0];
    const float lc = s[1] / denom;
    const float lx = s[2] / denom;
    const float ly = s[3] / denom;
    const float lw = s[4] / denom;
    const float lh = s[5] / denom;
    const float lf = s[6] / denom;
    out[0] = lc + lx + ly + lw + lh + lf;
    out[1] = lc;
    out[2] = lx;
    out[3] = ly;
    out[4] = lw;
    out[5] = lh;
    out[6] = lf;
  }
}

extern "C" void kernel_launch(void* const* d_in, const int* in_sizes, int n_in,
                              void* d_out, int out_size, void* d_ws, size_t ws_size,
                              hipStream_t stream) {
  const float* pred_boxes = (const float*)d_in[0];
  const float* pred_cls = (const float*)d_in[1];
  const float* target = (const float*)d_in[2];
  float* out = (float*)d_out;

  // workspace layout
  unsigned long long* rowwin = (unsigned long long*)d_ws;  // 16*32*128 u64
  float* ws2 = (float*)(rowwin + (size_t)N_ * CPW * M_);   // 16*8 floats
  int* cnt = (int*)(ws2 + N_ * 8);                         // 17 ints (0xAA)

  dim3 g(CPW, N_);
  fused_loss_kernel<<<g, 512, 0, stream>>>(pred_boxes, pred_cls, target,
                                           rowwin, ws2, cnt, out);
}

// Round 4
// 112.114 us; speedup vs baseline: 1.0107x; 1.0107x over previous
//
#include <hip/hip_runtime.h>
#include <math.h>

// Problem constants (from reference setup_inputs)
constexpr int N_ = 16;
constexpr int K_ = 32768;
constexpr int C_ = 16;
constexpr int M_ = 128;

constexpr int KC = 512;              // k's staged per pass
constexpr int CPB = 2;               // chunks (passes) per block
constexpr int CPW = K_ / (KC * CPB); // 32 blocks per n -> 512 blocks, 2/CU
constexpr int WAVES = 8;             // waves per block (512 threads)

// ws poison: harness re-poisons d_ws to 0xAA before every launch. cnt
// counters start at (int)0xAAAAAAAA (accept 0 base as fallback). rowwin
// slots are written unconditionally by every block before its release, so
// poison is never read there.
#define POISON_U 0xAAAAAAAAu

// Agent-scope accessors: coherence-point loads/stores, NO cache-wide wb/inv
// (R3 lesson: all-thread __threadfence() cost 3x).
__device__ __forceinline__ unsigned long long load_agent_u64(
    const unsigned long long* p) {
  return __hip_atomic_load(p, __ATOMIC_RELAXED, __HIP_MEMORY_SCOPE_AGENT);
}
__device__ __forceinline__ void store_agent_u64(unsigned long long* p,
                                                unsigned long long v) {
  __hip_atomic_store(p, v, __ATOMIC_RELAXED, __HIP_MEMORY_SCOPE_AGENT);
}
__device__ __forceinline__ void store_agent_f32(float* p, float v) {
  __hip_atomic_store(p, v, __ATOMIC_RELAXED, __HIP_MEMORY_SCOPE_AGENT);
}
__device__ __forceinline__ float load_agent_f32(const float* p) {
  return __hip_atomic_load(p, __ATOMIC_RELAXED, __HIP_MEMORY_SCOPE_AGENT);
}

// R16 (kept): single-instruction float min/max (bypass IEEE canonicalization
// hipcc inserts around fminf/fmaxf). Bit-exact for finite inputs.
__device__ __forceinline__ float vminf_(float a, float b) {
  float r;
  asm("v_min_f32 %0, %1, %2" : "=v"(r) : "v"(a), "v"(b));
  return r;
}
__device__ __forceinline__ float vmaxf_(float a, float b) {
  float r;
  asm("v_max_f32 %0, %1, %2" : "=v"(r) : "v"(a), "v"(b));
  return r;
}
__device__ __forceinline__ float vmax0_(float a) {  // max(a, 0.0f)
  float r;
  asm("v_max_f32 %0, 0, %1" : "=v"(r) : "v"(a));
  return r;
}
// key = (iou_bits & 0xFFFFFE00) | (idx6 & 0x1FF) in ONE v_bfi_b32.
__device__ __forceinline__ int vbfi_key_(unsigned mask, unsigned iou_bits,
                                         unsigned idx6) {
  int r;
  asm("v_bfi_b32 %0, %1, %2, %3" : "=v"(r) : "v"(mask), "v"(iou_bits),
      "v"(idx6));
  return r;
}
// R18: guaranteed single-instruction signed int max / 3-input max (the C
// ternary may compile to v_cmp(vcc)+v_cndmask — 2 ops + a VCC false
// dependency serializing the 4 independent j-chains).
__device__ __forceinline__ int vmaxi_(int a, int b) {
  int r;
  asm("v_max_i32 %0, %1, %2" : "=v"(r) : "v"(a), "v"(b));
  return r;
}
__device__ __forceinline__ int vmax3i_(int a, int b, int c) {
  int r;
  asm("v_max3_i32 %0, %1, %2, %3" : "=v"(r) : "v"(a), "v"(b), "v"(c));
  return r;
}

// ---------------------------------------------------------------------------
// R18 = R16 (best-known 112.6: single-buffer stage->bar->compute schedule,
// LDS staging, hoisted a1, 4 rows/lane ILP, asm min/max/bfi, packed-int-key
// argmax, CPB=2 in-register chunk merge, relaxed-store publish, absmax 0.0)
// with ALL int-max reductions forced to single VALU instructions:
//   * inner best-update: 2 kl per body folded with ONE v_max3_i32
//     (associative/commutative -> winner set bit-identical),
//   * 8-way wave merge: 7 ternaries -> 3x v_max3_i32 + 1 v_max_i32.
// R17 (dbuf + up-front loads) was neutral -> reverted; staging latency is
// already hidden by cross-block wave overlap. Target: the ~1.7x VALU
// instruction inflation + VCC-serialization of the 4 j-chains.
// ---------------------------------------------------------------------------
__global__ __launch_bounds__(512, 4) void fused_loss_kernel(
    const float* __restrict__ pred_boxes,
    const float* __restrict__ pred_cls,
    const float* __restrict__ target,
    unsigned long long* __restrict__ rowwin,  // [N_][CPW][M_]
    float* __restrict__ ws2,                  // [N_][8]
    int* __restrict__ cnt,                    // [N_+1]
    float* __restrict__ out) {
  __shared__ float4 lds4[KC];
  __shared__ float ldsa1[KC];
  __shared__ int key_s[WAVES][CPB][M_];
  __shared__ float red[WAVES][7];
  __shared__ int s_flag;

  const int bx = blockIdx.x;  // 0..CPW-1
  const int n = blockIdx.y;
  const int tid = threadIdx.x;

  const int wv = tid >> 6;          // wave id 0..7
  const int lane = tid & 63;
  const int rb = lane & 31;         // row base: rows rb + 32*j
  const int half = (lane >> 5) & 1; // k-half within the wave's slice pair
  const int ks = (wv * 2 + half) * 32;       // this lane's 32-k slice
  const int hbase = ((1 - half) << 5) | 31;  // idx6 = hbase - kl (bits 0-5)

  // per-lane target values for 4 rows (tboxes = target[...,1:]) — loaded
  // once, reused across both chunk passes.
  float tx1[4], ty1[4], tx2[4], ty2[4], a2[4];
#pragma unroll
  for (int j = 0; j < 4; ++j) {
    const float* tg = target + ((size_t)(n * M_ + rb + 32 * j)) * 5;
    tx1[j] = tg[1];
    ty1[j] = tg[2];
    tx2[j] = tg[3] + 1.0f;
    ty2[j] = tg[4] + 1.0f;
    a2[j] = (tg[3] - tg[1] + 1.0f) * (tg[4] - tg[2] + 1.0f) + 1e-16f;
  }

  const unsigned keymask = 0xFFFFFE00u;  // hoisted into a VGPR once

  for (int cc = 0; cc < CPB; ++cc) {
    const int k0 = (bx * CPB + cc) * KC;

    // ---- stage chunk: 512 k's, one per thread (ref-exact derived values) --
    {
      const float* p = pred_boxes + ((size_t)(n * K_ + k0 + tid)) * 5;
      const float x = p[0];
      const float y = p[1];
      const float bw = p[2];
      const float bh = p[3];
      const float px2 = bw + x;  // ref: pb[...,2] + pb[...,0]
      const float py2 = bh + y;
      lds4[tid] = make_float4(x, y, px2 + 1.0f, py2 + 1.0f);
      // ref-exact: a1 = (p_x2 - p_x1 + 1) * (p_y2 - p_y1 + 1)
      ldsa1[tid] = (px2 - x + 1.0f) * (py2 - y + 1.0f);
    }
    __syncthreads();

    int best[4];
#pragma unroll
    for (int j = 0; j < 4; ++j) best[j] = (int)0x80000000;

    // 2 k's per body; fold both keys with one v_max3_i32.
#pragma unroll 4
    for (int kl = 0; kl < 32; kl += 2) {
      const float4 va = lds4[ks + kl];     // broadcast ds_read_b128
      const float a1a = ldsa1[ks + kl];    // broadcast ds_read_b32
      const float4 vb = lds4[ks + kl + 1];
      const float a1b = ldsa1[ks + kl + 1];
      const unsigned idx6a = (unsigned)(hbase - kl);
      const unsigned idx6b = (unsigned)(hbase - (kl + 1));
#pragma unroll
      for (int j = 0; j < 4; ++j) {  // 4 independent chains x 2 k's
        float wwa = vminf_(va.z, tx2[j]) - vmaxf_(va.x, tx1[j]);
        float hha = vminf_(va.w, ty2[j]) - vmaxf_(va.y, ty1[j]);
        wwa = vmax0_(wwa);
        hha = vmax0_(hha);
        const float intera = wwa * hha;
        const float ioua =
            intera * __builtin_amdgcn_rcpf((a1a + a2[j]) - intera);
        const int keya = vbfi_key_(keymask, __float_as_uint(ioua), idx6a);

        float wwb = vminf_(vb.z, tx2[j]) - vmaxf_(vb.x, tx1[j]);
        float hhb = vminf_(vb.w, ty2[j]) - vmaxf_(vb.y, ty1[j]);
        wwb = vmax0_(wwb);
        hhb = vmax0_(hhb);
        const float interb = wwb * hhb;
        const float ioub =
            interb * __builtin_amdgcn_rcpf((a1b + a2[j]) - interb);
        const int keyb = vbfi_key_(keymask, __float_as_uint(ioub), idx6b);

        best[j] = vmax3i_(best[j], keya, keyb);
      }
    }

    // merge the two k-halves (lane ^ 32) in-register; bit5 tag keeps ranking
    // (iou desc, k asc) exact.
#pragma unroll
    for (int j = 0; j < 4; ++j) {
      const int other = __shfl_xor(best[j], 32, 64);
      best[j] = vmaxi_(best[j], other);
    }
    // lanes 0..31 publish 4 rows with (7-wv) in bits 6-8
    if (lane < 32) {
      const unsigned wvf = (unsigned)(7 - wv) << 6;
#pragma unroll
      for (int j = 0; j < 4; ++j) {
        const unsigned u = (unsigned)best[j];
        key_s[wv][cc][rb + 32 * j] = (int)((u & 0xFFFFFE00u) | wvf | (u & 63u));
      }
    }
    __syncthreads();  // key_s[.][cc] visible; lds4/ldsa1 free for restage
  }

  // 8-way wave merge per chunk (3x v_max3_i32 + v_max_i32), exact u64
  // cross-chunk merge in-register, then ONE relaxed agent store per row.
  if (tid < M_) {
    unsigned long long bestu = ~0ull;
#pragma unroll
    for (int cc = 0; cc < CPB; ++cc) {
      int mg = vmax3i_(key_s[0][cc][tid], key_s[1][cc][tid], key_s[2][cc][tid]);
      mg = vmax3i_(mg, key_s[3][cc][tid], key_s[4][cc][tid]);
      mg = vmax3i_(mg, key_s[5][cc][tid], key_s[6][cc][tid]);
      mg = vmaxi_(mg, key_s[7][cc][tid]);
      const unsigned e = (unsigned)mg & 511u;
      const int gk = (bx * CPB + cc) * KC + (511 - (int)e);  // winner's k
      const unsigned tr = (unsigned)mg & 0xFFFFFE00u;        // trunc iou bits
      const unsigned ord = tr ^ (unsigned)(((int)tr >> 31) | 0x80000000);
      const unsigned long long u =
          ((unsigned long long)(~ord) << 32) | (unsigned)gk;
      bestu = u < bestu ? u : bestu;  // ties -> smaller global k (cc=0 first)
    }
    store_agent_u64(&rowwin[((size_t)n * CPW + bx) * M_ + tid], bestu);
  }

  // Release: barrier drains each wave's vmcnt(0); then one relaxed signal.
  __syncthreads();
  if (tid == 0) {
    const unsigned old = (unsigned)atomicAdd(&cnt[n], 1);
    s_flag = (old == POISON_U + (CPW - 1)) || (old == CPW - 1);
  }
  __syncthreads();
  if (!s_flag) return;

  // ================= Phase 2: last block for this n =================
  {
    const int m = tid & (M_ - 1);
    float acc[7] = {0, 0, 0, 0, 0, 0, 0};
    if (tid < M_) {
      // merge the CPW slot keys (min == global first-max argmax)
      unsigned long long bestk = ~0ull;
#pragma unroll
      for (int g = 0; g < CPW; ++g) {
        const unsigned long long pk =
            load_agent_u64(&rowwin[((size_t)n * CPW + g) * M_ + m]);
        bestk = pk < bestk ? pk : bestk;
      }
      const int bidx0 = (int)(unsigned)bestk;  // low 32 bits = winning k

      const float* tg2 = target + ((size_t)(n * M_ + m)) * 5;
      const float t0 = tg2[0], t1 = tg2[1], t2 = tg2[2], t3 = tg2[3],
                  t4 = tg2[4];
      const float sum5 = t0 + t1 + t2 + t3 + t4;
      const float mk = (sum5 != 0.0f) ? 1.0f : 0.0f;
      const int bidx = (sum5 != 0.0f) ? bidx0 : 0;

      const float* pb = pred_boxes + ((size_t)(n * K_ + bidx)) * 5;
      const float b0 = pb[0], b1 = pb[1], bw = pb[2], bh = pb[3];

      // cross-entropy via log-softmax over C=16
      const float4* pc =
          (const float4*)(pred_cls + ((size_t)(n * K_ + bidx)) * C_);
      float vals[C_];
#pragma unroll
      for (int q = 0; q < 4; ++q) {
        const float4 vv = pc[q];
        vals[q * 4 + 0] = vv.x;
        vals[q * 4 + 1] = vv.y;
        vals[q * 4 + 2] = vv.z;
        vals[q * 4 + 3] = vv.w;
      }
      int tcls = (int)t0;
      tcls = tcls < 0 ? 0 : (tcls >= C_ ? C_ - 1 : tcls);
      float mx = -INFINITY;
#pragma unroll
      for (int q = 0; q < C_; ++q) mx = fmaxf(mx, vals[q]);
      float se = 0.0f;
#pragma unroll
      for (int q = 0; q < C_; ++q) se += expf(vals[q] - mx);
      const float ce2 = logf(se) + mx - vals[tcls];

      const float dx = b0 - t1;
      const float dy = b1 - t2;
      const float dw = bw - (t3 - t1);
      const float dh = bh - (t4 - t2);

      // conf: conf_idx==0 => sigmoid(pred_boxes[n,0,4]) for every m
      const float pcf = pred_boxes[(size_t)n * K_ * 5 + 4];
      const float bc = 1.0f / (1.0f + expf(-pcf));
      const float bce = (bc > 0.5f) ? -logf(bc) : -logf(1.0f - bc);

      acc[0] = mk;
      acc[1] = mk * ce2;
      acc[2] = mk * dx * dx;
      acc[3] = mk * dy * dy;
      acc[4] = mk * dw * dw;
      acc[5] = mk * dh * dh;
      acc[6] = mk * bce;
    }

    // block reduce: 8 waves shuffle-reduce, LDS combine
#pragma unroll
    for (int i = 0; i < 7; ++i) {
      float v = acc[i];
      for (int off = 32; off > 0; off >>= 1) v += __shfl_down(v, off, 64);
      acc[i] = v;
    }
    const int lane2 = tid & 63;
    const int wid = tid >> 6;
    if (lane2 == 0) {
#pragma unroll
      for (int i = 0; i < 7; ++i) red[wid][i] = acc[i];
    }
    __syncthreads();

    if (tid == 0) {
      float sum7[7];
#pragma unroll
      for (int i = 0; i < 7; ++i) {
        float s = 0.0f;
#pragma unroll
        for (int w2 = 0; w2 < WAVES; ++w2) s += red[w2][i];
        sum7[i] = s;
      }
#pragma unroll
      for (int i = 0; i < 7; ++i) store_agent_f32(&ws2[n * 8 + i], sum7[i]);
    }
    __syncthreads();  // release: drains tid0's stores before the signal
    if (tid == 0) {
      const unsigned old2 = (unsigned)atomicAdd(&cnt[N_], 1);
      s_flag = (old2 == POISON_U + (N_ - 1)) || (old2 == N_ - 1);
    }
    __syncthreads();
  }

  // ================= Phase 3: global finalizer =================
  if (s_flag && tid == 0) {
    float s[7] = {0, 0, 0, 0, 0, 0, 0};
    for (int nn = 0; nn < N_; ++nn)
#pragma unroll
      for (int i = 0; i < 7; ++i) s[i] += load_agent_f32(&ws2[nn * 8 + i]);
    const float denom = s[0];
    const float lc = s[1] / denom;
    const float lx = s[2] / denom;
    const float ly = s[3] / denom;
    const float lw = s[4] / denom;
    const float lh = s[5] / denom;
    const float lf = s[6] / denom;
    out[0] = lc + lx + ly + lw + lh + lf;
    out[1] = lc;
    out[2] = lx;
    out[3] = ly;
    out[4] = lw;
    out[5] = lh;
    out[6] = lf;
  }
}

extern "C" void kernel_launch(void* const* d_in, const int* in_sizes, int n_in,
                              void* d_out, int out_size, void* d_ws, size_t ws_size,
                              hipStream_t stream) {
  const float* pred_boxes = (const float*)d_in[0];
  const float* pred_cls = (const float*)d_in[1];
  const float* target = (const float*)d_in[2];
  float* out = (float*)d_out;

  // workspace layout
  unsigned long long* rowwin = (unsigned long long*)d_ws;  // 16*32*128 u64
  float* ws2 = (float*)(rowwin + (size_t)N_ * CPW * M_);   // 16*8 floats
  int* cnt = (int*)(ws2 + N_ * 8);                         // 17 ints (0xAA)

  dim3 g(CPW, N_);
  fused_loss_kernel<<<g, 512, 0, stream>>>(pred_boxes, pred_cls, target,
                                           rowwin, ws2, cnt, out);
}

// Round 5
// 111.738 us; speedup vs baseline: 1.0141x; 1.0034x over previous
//
#include <hip/hip_runtime.h>
#include <math.h>

// Problem constants (from reference setup_inputs)
constexpr int N_ = 16;
constexpr int K_ = 32768;
constexpr int C_ = 16;
constexpr int M_ = 128;

constexpr int KC = 512;              // k's staged per pass
constexpr int CPB = 2;               // chunks (passes) per block
constexpr int CPW = K_ / (KC * CPB); // 32 blocks per n -> 512 blocks, 2/CU
constexpr int WAVES = 8;             // waves per block (512 threads)

// ws poison: harness re-poisons d_ws to 0xAA before every launch. cnt
// counters start at (int)0xAAAAAAAA (accept 0 base as fallback). rowwin
// slots are written unconditionally by every block before its release, so
// poison is never read there.
#define POISON_U 0xAAAAAAAAu

// Agent-scope accessors: coherence-point loads/stores, NO cache-wide wb/inv
// (R3 lesson: all-thread __threadfence() cost 3x).
__device__ __forceinline__ unsigned long long load_agent_u64(
    const unsigned long long* p) {
  return __hip_atomic_load(p, __ATOMIC_RELAXED, __HIP_MEMORY_SCOPE_AGENT);
}
__device__ __forceinline__ void store_agent_u64(unsigned long long* p,
                                                unsigned long long v) {
  __hip_atomic_store(p, v, __ATOMIC_RELAXED, __HIP_MEMORY_SCOPE_AGENT);
}
__device__ __forceinline__ void store_agent_f32(float* p, float v) {
  __hip_atomic_store(p, v, __ATOMIC_RELAXED, __HIP_MEMORY_SCOPE_AGENT);
}
__device__ __forceinline__ float load_agent_f32(const float* p) {
  return __hip_atomic_load(p, __ATOMIC_RELAXED, __HIP_MEMORY_SCOPE_AGENT);
}

// R16 (kept): single-instruction float min/max (bypass IEEE canonicalization
// hipcc inserts around fminf/fmaxf). Bit-exact for finite inputs.
__device__ __forceinline__ float vminf_(float a, float b) {
  float r;
  asm("v_min_f32 %0, %1, %2" : "=v"(r) : "v"(a), "v"(b));
  return r;
}
__device__ __forceinline__ float vmaxf_(float a, float b) {
  float r;
  asm("v_max_f32 %0, %1, %2" : "=v"(r) : "v"(a), "v"(b));
  return r;
}
__device__ __forceinline__ float vmax0_(float a) {  // max(a, 0.0f)
  float r;
  asm("v_max_f32 %0, 0, %1" : "=v"(r) : "v"(a));
  return r;
}
// key = (iou_bits & 0xFFFFFE00) | (idx6 & 0x1FF) in ONE v_bfi_b32.
__device__ __forceinline__ int vbfi_key_(unsigned mask, unsigned iou_bits,
                                         unsigned idx6) {
  int r;
  asm("v_bfi_b32 %0, %1, %2, %3" : "=v"(r) : "v"(mask), "v"(iou_bits),
      "v"(idx6));
  return r;
}
// R18 (kept): guaranteed single-instruction signed int max / 3-input max.
__device__ __forceinline__ int vmaxi_(int a, int b) {
  int r;
  asm("v_max_i32 %0, %1, %2" : "=v"(r) : "v"(a), "v"(b));
  return r;
}
__device__ __forceinline__ int vmax3i_(int a, int b, int c) {
  int r;
  asm("v_max3_i32 %0, %1, %2, %3" : "=v"(r) : "v"(a), "v"(b), "v"(c));
  return r;
}

// ---------------------------------------------------------------------------
// R19 = R18 (best-known: LDS staging, hoisted a1, 4 rows/lane ILP, asm
// min/max/bfi/max3, packed-int-key argmax, CPB=2 in-register chunk merge,
// relaxed-store publish, absmax 0.0) with the inner loop SOFTWARE-PIPELINED:
//   * VGPR_Count=40 showed the compiler schedules each 2-k body as
//     load -> lgkmcnt wait (~64-120cy exposed) -> compute; all waves stall
//     in phase -> the measured ~2.5x issue dilation at flat 53% VALUBusy.
//   * Fix: prefetch body i+1's operands (va/vb/a1 pair) into named regs
//     BEFORE computing body i (full unroll, compile-time guards) — source
//     order forces load-use distance the scheduler wouldn't create.
//   * a1 pair read as ONE ds_read_b64 (float2 at even index, always
//     8B-aligned) instead of 2x ds_read_b32: 4 -> 3 LDS instr/body.
// Numerics byte-identical to R18.
// ---------------------------------------------------------------------------
__global__ __launch_bounds__(512, 4) void fused_loss_kernel(
    const float* __restrict__ pred_boxes,
    const float* __restrict__ pred_cls,
    const float* __restrict__ target,
    unsigned long long* __restrict__ rowwin,  // [N_][CPW][M_]
    float* __restrict__ ws2,                  // [N_][8]
    int* __restrict__ cnt,                    // [N_+1]
    float* __restrict__ out) {
  __shared__ float4 lds4[KC];
  __shared__ float ldsa1[KC];
  __shared__ int key_s[WAVES][CPB][M_];
  __shared__ float red[WAVES][7];
  __shared__ int s_flag;

  const int bx = blockIdx.x;  // 0..CPW-1
  const int n = blockIdx.y;
  const int tid = threadIdx.x;

  const int wv = tid >> 6;          // wave id 0..7
  const int lane = tid & 63;
  const int rb = lane & 31;         // row base: rows rb + 32*j
  const int half = (lane >> 5) & 1; // k-half within the wave's slice pair
  const int ks = (wv * 2 + half) * 32;       // this lane's 32-k slice
  const int hbase = ((1 - half) << 5) | 31;  // idx6 = hbase - kl (bits 0-5)

  // per-lane target values for 4 rows (tboxes = target[...,1:]) — loaded
  // once, reused across both chunk passes.
  float tx1[4], ty1[4], tx2[4], ty2[4], a2[4];
#pragma unroll
  for (int j = 0; j < 4; ++j) {
    const float* tg = target + ((size_t)(n * M_ + rb + 32 * j)) * 5;
    tx1[j] = tg[1];
    ty1[j] = tg[2];
    tx2[j] = tg[3] + 1.0f;
    ty2[j] = tg[4] + 1.0f;
    a2[j] = (tg[3] - tg[1] + 1.0f) * (tg[4] - tg[2] + 1.0f) + 1e-16f;
  }

  const unsigned keymask = 0xFFFFFE00u;  // hoisted into a VGPR once

  for (int cc = 0; cc < CPB; ++cc) {
    const int k0 = (bx * CPB + cc) * KC;

    // ---- stage chunk: 512 k's, one per thread (ref-exact derived values) --
    {
      const float* p = pred_boxes + ((size_t)(n * K_ + k0 + tid)) * 5;
      const float x = p[0];
      const float y = p[1];
      const float bw = p[2];
      const float bh = p[3];
      const float px2 = bw + x;  // ref: pb[...,2] + pb[...,0]
      const float py2 = bh + y;
      lds4[tid] = make_float4(x, y, px2 + 1.0f, py2 + 1.0f);
      // ref-exact: a1 = (p_x2 - p_x1 + 1) * (p_y2 - p_y1 + 1)
      ldsa1[tid] = (px2 - x + 1.0f) * (py2 - y + 1.0f);
    }
    __syncthreads();

    int best[4];
#pragma unroll
    for (int j = 0; j < 4; ++j) best[j] = (int)0x80000000;

    // ---- software-pipelined: prefetch body kl+2 while computing body kl --
    float4 va = lds4[ks + 0];
    float4 vb = lds4[ks + 1];
    float2 a1p = *(const float2*)&ldsa1[ks + 0];  // {a1a, a1b}, 8B aligned

#pragma unroll
    for (int kl = 0; kl < 32; kl += 2) {
      float4 nva, nvb;
      float2 na1p;
      if (kl + 2 < 32) {  // compile-time under full unroll
        nva = lds4[ks + kl + 2];
        nvb = lds4[ks + kl + 3];
        na1p = *(const float2*)&ldsa1[ks + kl + 2];
      }
      const float a1a = a1p.x;
      const float a1b = a1p.y;
      const unsigned idx6a = (unsigned)(hbase - kl);
      const unsigned idx6b = (unsigned)(hbase - (kl + 1));
#pragma unroll
      for (int j = 0; j < 4; ++j) {  // 4 independent chains x 2 k's
        float wwa = vminf_(va.z, tx2[j]) - vmaxf_(va.x, tx1[j]);
        float hha = vminf_(va.w, ty2[j]) - vmaxf_(va.y, ty1[j]);
        wwa = vmax0_(wwa);
        hha = vmax0_(hha);
        const float intera = wwa * hha;
        const float ioua =
            intera * __builtin_amdgcn_rcpf((a1a + a2[j]) - intera);
        const int keya = vbfi_key_(keymask, __float_as_uint(ioua), idx6a);

        float wwb = vminf_(vb.z, tx2[j]) - vmaxf_(vb.x, tx1[j]);
        float hhb = vminf_(vb.w, ty2[j]) - vmaxf_(vb.y, ty1[j]);
        wwb = vmax0_(wwb);
        hhb = vmax0_(hhb);
        const float interb = wwb * hhb;
        const float ioub =
            interb * __builtin_amdgcn_rcpf((a1b + a2[j]) - interb);
        const int keyb = vbfi_key_(keymask, __float_as_uint(ioub), idx6b);

        best[j] = vmax3i_(best[j], keya, keyb);
      }
      if (kl + 2 < 32) {
        va = nva;
        vb = nvb;
        a1p = na1p;
      }
    }

    // merge the two k-halves (lane ^ 32) in-register; bit5 tag keeps ranking
    // (iou desc, k asc) exact.
#pragma unroll
    for (int j = 0; j < 4; ++j) {
      const int other = __shfl_xor(best[j], 32, 64);
      best[j] = vmaxi_(best[j], other);
    }
    // lanes 0..31 publish 4 rows with (7-wv) in bits 6-8
    if (lane < 32) {
      const unsigned wvf = (unsigned)(7 - wv) << 6;
#pragma unroll
      for (int j = 0; j < 4; ++j) {
        const unsigned u = (unsigned)best[j];
        key_s[wv][cc][rb + 32 * j] = (int)((u & 0xFFFFFE00u) | wvf | (u & 63u));
      }
    }
    __syncthreads();  // key_s[.][cc] visible; lds4/ldsa1 free for restage
  }

  // 8-way wave merge per chunk (3x v_max3_i32 + v_max_i32), exact u64
  // cross-chunk merge in-register, then ONE relaxed agent store per row.
  if (tid < M_) {
    unsigned long long bestu = ~0ull;
#pragma unroll
    for (int cc = 0; cc < CPB; ++cc) {
      int mg = vmax3i_(key_s[0][cc][tid], key_s[1][cc][tid], key_s[2][cc][tid]);
      mg = vmax3i_(mg, key_s[3][cc][tid], key_s[4][cc][tid]);
      mg = vmax3i_(mg, key_s[5][cc][tid], key_s[6][cc][tid]);
      mg = vmaxi_(mg, key_s[7][cc][tid]);
      const unsigned e = (unsigned)mg & 511u;
      const int gk = (bx * CPB + cc) * KC + (511 - (int)e);  // winner's k
      const unsigned tr = (unsigned)mg & 0xFFFFFE00u;        // trunc iou bits
      const unsigned ord = tr ^ (unsigned)(((int)tr >> 31) | 0x80000000);
      const unsigned long long u =
          ((unsigned long long)(~ord) << 32) | (unsigned)gk;
      bestu = u < bestu ? u : bestu;  // ties -> smaller global k (cc=0 first)
    }
    store_agent_u64(&rowwin[((size_t)n * CPW + bx) * M_ + tid], bestu);
  }

  // Release: barrier drains each wave's vmcnt(0); then one relaxed signal.
  __syncthreads();
  if (tid == 0) {
    const unsigned old = (unsigned)atomicAdd(&cnt[n], 1);
    s_flag = (old == POISON_U + (CPW - 1)) || (old == CPW - 1);
  }
  __syncthreads();
  if (!s_flag) return;

  // ================= Phase 2: last block for this n =================
  {
    const int m = tid & (M_ - 1);
    float acc[7] = {0, 0, 0, 0, 0, 0, 0};
    if (tid < M_) {
      // merge the CPW slot keys (min == global first-max argmax)
      unsigned long long bestk = ~0ull;
#pragma unroll
      for (int g = 0; g < CPW; ++g) {
        const unsigned long long pk =
            load_agent_u64(&rowwin[((size_t)n * CPW + g) * M_ + m]);
        bestk = pk < bestk ? pk : bestk;
      }
      const int bidx0 = (int)(unsigned)bestk;  // low 32 bits = winning k

      const float* tg2 = target + ((size_t)(n * M_ + m)) * 5;
      const float t0 = tg2[0], t1 = tg2[1], t2 = tg2[2], t3 = tg2[3],
                  t4 = tg2[4];
      const float sum5 = t0 + t1 + t2 + t3 + t4;
      const float mk = (sum5 != 0.0f) ? 1.0f : 0.0f;
      const int bidx = (sum5 != 0.0f) ? bidx0 : 0;

      const float* pb = pred_boxes + ((size_t)(n * K_ + bidx)) * 5;
      const float b0 = pb[0], b1 = pb[1], bw = pb[2], bh = pb[3];

      // cross-entropy via log-softmax over C=16
      const float4* pc =
          (const float4*)(pred_cls + ((size_t)(n * K_ + bidx)) * C_);
      float vals[C_];
#pragma unroll
      for (int q = 0; q < 4; ++q) {
        const float4 vv = pc[q];
        vals[q * 4 + 0] = vv.x;
        vals[q * 4 + 1] = vv.y;
        vals[q * 4 + 2] = vv.z;
        vals[q * 4 + 3] = vv.w;
      }
      int tcls = (int)t0;
      tcls = tcls < 0 ? 0 : (tcls >= C_ ? C_ - 1 : tcls);
      float mx = -INFINITY;
#pragma unroll
      for (int q = 0; q < C_; ++q) mx = fmaxf(mx, vals[q]);
      float se = 0.0f;
#pragma unroll
      for (int q = 0; q < C_; ++q) se += expf(vals[q] - mx);
      const float ce2 = logf(se) + mx - vals[tcls];

      const float dx = b0 - t1;
      const float dy = b1 - t2;
      const float dw = bw - (t3 - t1);
      const float dh = bh - (t4 - t2);

      // conf: conf_idx==0 => sigmoid(pred_boxes[n,0,4]) for every m
      const float pcf = pred_boxes[(size_t)n * K_ * 5 + 4];
      const float bc = 1.0f / (1.0f + expf(-pcf));
      const float bce = (bc > 0.5f) ? -logf(bc) : -logf(1.0f - bc);

      acc[0] = mk;
      acc[1] = mk * ce2;
      acc[2] = mk * dx * dx;
      acc[3] = mk * dy * dy;
      acc[4] = mk * dw * dw;
      acc[5] = mk * dh * dh;
      acc[6] = mk * bce;
    }

    // block reduce: 8 waves shuffle-reduce, LDS combine
#pragma unroll
    for (int i = 0; i < 7; ++i) {
      float v = acc[i];
      for (int off = 32; off > 0; off >>= 1) v += __shfl_down(v, off, 64);
      acc[i] = v;
    }
    const int lane2 = tid & 63;
    const int wid = tid >> 6;
    if (lane2 == 0) {
#pragma unroll
      for (int i = 0; i < 7; ++i) red[wid][i] = acc[i];
    }
    __syncthreads();

    if (tid == 0) {
      float sum7[7];
#pragma unroll
      for (int i = 0; i < 7; ++i) {
        float s = 0.0f;
#pragma unroll
        for (int w2 = 0; w2 < WAVES; ++w2) s += red[w2][i];
        sum7[i] = s;
      }
#pragma unroll
      for (int i = 0; i < 7; ++i) store_agent_f32(&ws2[n * 8 + i], sum7[i]);
    }
    __syncthreads();  // release: drains tid0's stores before the signal
    if (tid == 0) {
      const unsigned old2 = (unsigned)atomicAdd(&cnt[N_], 1);
      s_flag = (old2 == POISON_U + (N_ - 1)) || (old2 == N_ - 1);
    }
    __syncthreads();
  }

  // ================= Phase 3: global finalizer =================
  if (s_flag && tid == 0) {
    float s[7] = {0, 0, 0, 0, 0, 0, 0};
    for (int nn = 0; nn < N_; ++nn)
#pragma unroll
      for (int i = 0; i < 7; ++i) s[i] += load_agent_f32(&ws2[nn * 8 + i]);
    const float denom = s[0];
    const float lc = s[1] / denom;
    const float lx = s[2] / denom;
    const float ly = s[3] / denom;
    const float lw = s[4] / denom;
    const float lh = s[5] / denom;
    const float lf = s[6] / denom;
    out[0] = lc + lx + ly + lw + lh + lf;
    out[1] = lc;
    out[2] = lx;
    out[3] = ly;
    out[4] = lw;
    out[5] = lh;
    out[6] = lf;
  }
}

extern "C" void kernel_launch(void* const* d_in, const int* in_sizes, int n_in,
                              void* d_out, int out_size, void* d_ws, size_t ws_size,
                              hipStream_t stream) {
  const float* pred_boxes = (const float*)d_in[0];
  const float* pred_cls = (const float*)d_in[1];
  const float* target = (const float*)d_in[2];
  float* out = (float*)d_out;

  // workspace layout
  unsigned long long* rowwin = (unsigned long long*)d_ws;  // 16*32*128 u64
  float* ws2 = (float*)(rowwin + (size_t)N_ * CPW * M_);   // 16*8 floats
  int* cnt = (int*)(ws2 + N_ * 8);                         // 17 ints (0xAA)

  dim3 g(CPW, N_);
  fused_loss_kernel<<<g, 512, 0, stream>>>(pred_boxes, pred_cls, target,
                                           rowwin, ws2, cnt, out);
}